// Round 1
// baseline (2487.354 us; speedup 1.0000x reference)
//
#include <hip/hip_runtime.h>

typedef unsigned short u16;
typedef unsigned int   u32;
typedef __attribute__((ext_vector_type(8))) short short8;
typedef __attribute__((ext_vector_type(4))) float f32x4;

#define DD      768
#define KK      6144   /* 8*768 : [root | W0..W6] concatenated on K */
#define NREL    7
#define NLAYERS 5

__device__ __forceinline__ float b2f(u16 v) {
  return __uint_as_float(((u32)v) << 16);
}
__device__ __forceinline__ u16 f2bf(float f) {
  u32 x = __float_as_uint(f);
  x += 0x7fffu + ((x >> 16) & 1u);
  return (u16)(x >> 16);
}
__device__ __forceinline__ void gload16(const void* g, void* l) {
  __builtin_amdgcn_global_load_lds(
      (const __attribute__((address_space(1))) void*)g,
      (__attribute__((address_space(3))) void*)l, 16, 0, 0);
}

// ---------- setup kernels ----------

__global__ void cast_x_kernel(const float* __restrict__ x, u16* __restrict__ H, size_t n) {
  for (size_t i = ((size_t)blockIdx.x * 256 + threadIdx.x) * 4; i < n; i += (size_t)gridDim.x * 256 * 4) {
    float4 v = *(const float4*)&x[i];
    u32 lo = (u32)f2bf(v.x) | ((u32)f2bf(v.y) << 16);
    u32 hi = (u32)f2bf(v.z) | ((u32)f2bf(v.w) << 16);
    uint2 o; o.x = lo; o.y = hi;
    *(uint2*)&H[i] = o;
  }
}

__global__ void count_kernel(const int* __restrict__ eidx, const int* __restrict__ etype,
                             int* cnt_dst, int* cnt_rel, int E, int Nn) {
  int e = blockIdx.x * 256 + threadIdx.x;
  if (e >= E) return;
  int dst = eidx[E + e];
  int rel = etype[e] + 1;
  atomicAdd(&cnt_dst[dst], 1);
  atomicAdd(&cnt_rel[(size_t)rel * Nn + dst], 1);
}

__global__ __launch_bounds__(1024) void scan_kernel(const int* __restrict__ cnt, int* __restrict__ offs, int n) {
  __shared__ int part[1024];
  int t = threadIdx.x;
  int per = (n + 1023) / 1024;
  int base = t * per;
  int s = 0;
  for (int i = 0; i < per; ++i) { int idx = base + i; if (idx < n) s += cnt[idx]; }
  part[t] = s;
  __syncthreads();
  for (int o = 1; o < 1024; o <<= 1) {
    int v = (t >= o) ? part[t - o] : 0;
    __syncthreads();
    part[t] += v;
    __syncthreads();
  }
  int excl = (t == 0) ? 0 : part[t - 1];
  s = excl;
  for (int i = 0; i < per; ++i) { int idx = base + i; if (idx < n) { offs[idx] = s; s += cnt[idx]; } }
  if (t == 1023) offs[n] = part[1023];
}

__global__ void fillperm_kernel(const int* __restrict__ eidx, const int* __restrict__ offs,
                                int* fill, int* perm, int E) {
  int e = blockIdx.x * 256 + threadIdx.x;
  if (e >= E) return;
  int dst = eidx[E + e];
  int pos = offs[dst] + atomicAdd(&fill[dst], 1);
  perm[pos] = e;
}

// Per-layer weight conversion: Bt[n][seg*768+kk] = bf16( seg==0 ? roots[kk][n] : W[seg-1][kk][n] )
__global__ void wcat_kernel(const float* __restrict__ W, const float* __restrict__ R, u16* __restrict__ Bt) {
  __shared__ float t[32 * 33];
  int b = blockIdx.x;
  int s = b / 576, rem = b % 576;
  int kt = rem / 24, nt = rem % 24;
  const float* src = (s == 0) ? R : (W + (size_t)(s - 1) * DD * DD);
  int tj = threadIdx.x & 31, ti = threadIdx.x >> 5;  // ti 0..7
#pragma unroll
  for (int i = 0; i < 4; ++i) {
    int kk = kt * 32 + ti + i * 8;
    t[(ti + i * 8) * 33 + tj] = src[(size_t)kk * DD + nt * 32 + tj];
  }
  __syncthreads();
#pragma unroll
  for (int i = 0; i < 4; ++i) {
    int nn_ = nt * 32 + ti + i * 8;
    Bt[(size_t)nn_ * KK + (size_t)s * DD + kt * 32 + tj] = f2bf(t[tj * 33 + ti + i * 8]);
  }
}

// Copy h rows into segment 0 of A_cat
__global__ void copy_h_kernel(const u16* __restrict__ Hin, u16* __restrict__ Acat, int nn) {
  size_t total = (size_t)nn * (DD / 8);
  for (size_t i = (size_t)blockIdx.x * 256 + threadIdx.x; i < total; i += (size_t)gridDim.x * 256) {
    size_t r = i / (DD / 8), c = i % (DD / 8);
    *(uint4*)&Acat[r * KK + c * 8] = *(const uint4*)&Hin[r * DD + c * 8];
  }
}

// One block per destination node: accumulate incoming h[src] into LDS f32 [7][768],
// divide by per-relation counts, write bf16 into A_cat segments 1..7.
__global__ __launch_bounds__(256) void aggregate_kernel(
    const u16* __restrict__ H, const int* __restrict__ esrc, const int* __restrict__ etype,
    const int* __restrict__ offs, const int* __restrict__ perm, const int* __restrict__ cnt_rel,
    u16* __restrict__ Acat, int node0, int Nn, int writeAll) {
  __shared__ float acc[NREL * DD];
  int v = node0 + blockIdx.x;
  int t = threadIdx.x;
  int j0 = t * 3;  // 256*3 = 768
  for (int i = t; i < NREL * DD; i += 256) acc[i] = 0.f;
  __syncthreads();
  int beg = offs[v], end = offs[v + 1];
  for (int e = beg; e < end; ++e) {
    int eid = perm[e];
    int src = esrc[eid];
    int rel = etype[eid] + 1;
    const u16* hr = H + (size_t)src * DD + j0;
    float* a = acc + rel * DD + j0;
    a[0] += b2f(hr[0]);
    a[1] += b2f(hr[1]);
    a[2] += b2f(hr[2]);
  }
  __syncthreads();
  size_t rowbase = (size_t)blockIdx.x * KK;
  for (int r = 0; r < NREL; ++r) {
    int c = cnt_rel[(size_t)r * Nn + v];
    if (c > 0 || writeAll) {
      float inv = (c > 0) ? 1.f / (float)c : 0.f;
      const float* a = acc + r * DD + j0;
      u16* o = Acat + rowbase + (size_t)(r + 1) * DD + j0;
      o[0] = f2bf(a[0] * inv);
      o[1] = f2bf(a[1] * inv);
      o[2] = f2bf(a[2] * inv);
    }
  }
}

// 128x128-tile bf16 MFMA GEMM, K=6144. A [Mc][6144] row-major bf16, Bt = B^T [768][6144].
// Epilogue: + bias, ReLU, write bf16 h_next and/or f32 final out.
__global__ __launch_bounds__(256) void gemm_kernel(
    const u16* __restrict__ A, const u16* __restrict__ Bt, const float* __restrict__ bias,
    u16* __restrict__ Hout, float* __restrict__ Cout, int Mvalid) {
  __shared__ u16 lA[128 * 32];
  __shared__ u16 lB[128 * 32];
  int tid = threadIdx.x;
  int lane = tid & 63, wave = tid >> 6;
  int wm = wave >> 1, wn = wave & 1;
  int bm = blockIdx.x, bn = blockIdx.y;

  f32x4 acc[4][4];
#pragma unroll
  for (int i = 0; i < 4; ++i)
#pragma unroll
    for (int j = 0; j < 4; ++j) acc[i][j] = (f32x4){0.f, 0.f, 0.f, 0.f};

  // staging: tile is 128 rows x 64 bytes; each thread stages 2x16B for A and B
  int off0 = wave * 1024 + lane * 16;  // bytes within tile
  int off1 = off0 + 4096;
  int r0 = off0 >> 6, c0 = off0 & 63;
  int r1 = off1 >> 6, c1 = off1 & 63;
  const char* gA0 = (const char*)A + ((size_t)(bm * 128 + r0) * KK) * 2 + c0;
  const char* gA1 = (const char*)A + ((size_t)(bm * 128 + r1) * KK) * 2 + c1;
  const char* gB0 = (const char*)Bt + ((size_t)(bn * 128 + r0) * KK) * 2 + c0;
  const char* gB1 = (const char*)Bt + ((size_t)(bn * 128 + r1) * KK) * 2 + c1;
  u16* lA0 = lA + off0 / 2;
  u16* lA1 = lA + off1 / 2;
  u16* lB0 = lB + off0 / 2;
  u16* lB1 = lB + off1 / 2;

  int rsel = lane & 15, ksel = (lane >> 4) * 8;

  for (int k0 = 0; k0 < KK; k0 += 32) {
    __syncthreads();
    gload16(gA0 + (size_t)k0 * 2, lA0);
    gload16(gA1 + (size_t)k0 * 2, lA1);
    gload16(gB0 + (size_t)k0 * 2, lB0);
    gload16(gB1 + (size_t)k0 * 2, lB1);
    __syncthreads();
    short8 a[4], b[4];
#pragma unroll
    for (int m = 0; m < 4; ++m)
      a[m] = *(const short8*)&lA[(wm * 64 + m * 16 + rsel) * 32 + ksel];
#pragma unroll
    for (int n = 0; n < 4; ++n)
      b[n] = *(const short8*)&lB[(wn * 64 + n * 16 + rsel) * 32 + ksel];
#pragma unroll
    for (int m = 0; m < 4; ++m)
#pragma unroll
      for (int n = 0; n < 4; ++n)
        acc[m][n] = __builtin_amdgcn_mfma_f32_16x16x32_bf16(a[m], b[n], acc[m][n], 0, 0, 0);
  }

  int rif = (lane >> 4) * 4;
  int colb = bn * 128 + wn * 64 + (lane & 15);
#pragma unroll
  for (int m = 0; m < 4; ++m) {
    int rb = bm * 128 + wm * 64 + m * 16 + rif;
#pragma unroll
    for (int n = 0; n < 4; ++n) {
      int c = colb + n * 16;
      float bv = bias[c];
#pragma unroll
      for (int j = 0; j < 4; ++j) {
        int r = rb + j;
        if (r < Mvalid) {
          float v = acc[m][n][j] + bv;
          v = v > 0.f ? v : 0.f;
          if (Hout) Hout[(size_t)r * DD + c] = f2bf(v);
          if (Cout) Cout[(size_t)r * DD + c] = v;
        }
      }
    }
  }
}

// ---------- host ----------

static inline size_t alignup(size_t x, size_t a) { return (x + a - 1) & ~(a - 1); }

extern "C" void kernel_launch(void* const* d_in, const int* in_sizes, int n_in,
                              void* d_out, int out_size, void* d_ws, size_t ws_size,
                              hipStream_t stream) {
  const float* x       = (const float*)d_in[0];
  const int*   eidx    = (const int*)d_in[1];
  const int*   etype   = (const int*)d_in[2];
  const float* weights = (const float*)d_in[3];
  const float* roots   = (const float*)d_in[4];
  const float* biases  = (const float*)d_in[5];
  float* out = (float*)d_out;

  const int Nn = in_sizes[0] / DD;  // 20000
  const int E  = in_sizes[2];       // 100000

  char* p = (char*)d_ws;
  size_t off = 0;
  auto carve = [&](size_t bytes) -> char* {
    char* r = p + off;
    off = alignup(off + bytes, 256);
    return r;
  };
  u16* H0      = (u16*)carve((size_t)Nn * DD * 2);
  u16* Bt      = (u16*)carve((size_t)DD * KK * 2);
  int* cnt_rel = (int*)carve((size_t)NREL * Nn * 4);
  int* cnt_dst = (int*)carve((size_t)Nn * 4);
  int* offs    = (int*)carve((size_t)(Nn + 1) * 4);
  int* fill    = (int*)carve((size_t)Nn * 4);
  int* perm    = (int*)carve((size_t)E * 4);

  size_t rem = (ws_size > off) ? (ws_size - off) : 0;
  int McCap = (int)(rem / ((size_t)KK * 2));
  int Mpad_need = ((Nn + 127) / 128) * 128;
  int Mc = (McCap < Mpad_need) ? (McCap & ~127) : Mpad_need;
  if (Mc < 128) return;  // workspace too small — fail visibly rather than corrupt
  u16* Acat = (u16*)(p + off);
  int nchunks = (Nn + Mc - 1) / Mc;
  int writeAll = (nchunks > 1) ? 1 : 0;
  u16* H1 = (u16*)d_out;  // bf16 ping buffer inside d_out (out_size*4 >= Nn*DD*2)

  (void)hipMemsetAsync(cnt_rel, 0, (size_t)NREL * Nn * 4, stream);
  (void)hipMemsetAsync(cnt_dst, 0, (size_t)Nn * 4, stream);
  (void)hipMemsetAsync(fill, 0, (size_t)Nn * 4, stream);
  if (!writeAll) (void)hipMemsetAsync(Acat, 0, (size_t)Mc * KK * 2, stream);

  int eg = (E + 255) / 256;
  count_kernel<<<eg, 256, 0, stream>>>(eidx, etype, cnt_dst, cnt_rel, E, Nn);
  scan_kernel<<<1, 1024, 0, stream>>>(cnt_dst, offs, Nn);
  fillperm_kernel<<<eg, 256, 0, stream>>>(eidx, offs, fill, perm, E);
  cast_x_kernel<<<2048, 256, 0, stream>>>(x, H0, (size_t)Nn * DD);

  const u16* Hin = H0;
  u16* Hnext = H1;
  for (int l = 0; l < NLAYERS; ++l) {
    wcat_kernel<<<8 * 576, 256, 0, stream>>>(weights + (size_t)l * NREL * DD * DD,
                                             roots + (size_t)l * DD * DD, Bt);
    for (int c = 0; c < nchunks; ++c) {
      int node0 = c * Mc;
      int nn = (Nn - node0 < Mc) ? (Nn - node0) : Mc;
      int copy16 = nn * (DD / 8);
      int cb = (copy16 + 255) / 256;
      if (cb > 2048) cb = 2048;
      copy_h_kernel<<<cb, 256, 0, stream>>>(Hin + (size_t)node0 * DD, Acat, nn);
      aggregate_kernel<<<nn, 256, 0, stream>>>(Hin, eidx, etype, offs, perm, cnt_rel,
                                               Acat, node0, Nn, writeAll);
      dim3 gg((nn + 127) / 128, DD / 128);
      u16* ho = (l < NLAYERS - 1) ? (Hnext + (size_t)node0 * DD) : nullptr;
      float* co = (l == NLAYERS - 1) ? (out + (size_t)node0 * DD) : nullptr;
      gemm_kernel<<<gg, 256, 0, stream>>>(Acat, Bt, biases + (size_t)l * DD, ho, co, nn);
    }
    const u16* t_ = Hin;
    Hin = Hnext;
    Hnext = (u16*)t_;
  }
}

// Round 2
// 1548.090 us; speedup vs baseline: 1.6067x; 1.6067x over previous
//
#include <hip/hip_runtime.h>

typedef unsigned short u16;
typedef unsigned int   u32;
typedef __attribute__((ext_vector_type(8))) short short8;
typedef __attribute__((ext_vector_type(4))) float f32x4;

#define DD      768
#define KK      6144   /* 8*768 : [root | W0..W6] concatenated on K */
#define NREL    7
#define NLAYERS 5

__device__ __forceinline__ float b2f(u16 v) {
  return __uint_as_float(((u32)v) << 16);
}
__device__ __forceinline__ u16 f2bf(float f) {
  u32 x = __float_as_uint(f);
  x += 0x7fffu + ((x >> 16) & 1u);
  return (u16)(x >> 16);
}
__device__ __forceinline__ void gload16(const void* g, void* l) {
  __builtin_amdgcn_global_load_lds(
      (const __attribute__((address_space(1))) void*)g,
      (__attribute__((address_space(3))) void*)l, 16, 0, 0);
}

// ---------- setup kernels ----------

__global__ void cast_x_kernel(const float* __restrict__ x, u16* __restrict__ H, size_t n) {
  for (size_t i = ((size_t)blockIdx.x * 256 + threadIdx.x) * 4; i < n; i += (size_t)gridDim.x * 256 * 4) {
    float4 v = *(const float4*)&x[i];
    u32 lo = (u32)f2bf(v.x) | ((u32)f2bf(v.y) << 16);
    u32 hi = (u32)f2bf(v.z) | ((u32)f2bf(v.w) << 16);
    uint2 o; o.x = lo; o.y = hi;
    *(uint2*)&H[i] = o;
  }
}

__global__ void count_kernel(const int* __restrict__ eidx, const int* __restrict__ etype,
                             int* cnt_dst, int* cnt_rel, int E, int Nn) {
  int e = blockIdx.x * 256 + threadIdx.x;
  if (e >= E) return;
  int dst = eidx[E + e];
  int rel = etype[e] + 1;
  atomicAdd(&cnt_dst[dst], 1);
  atomicAdd(&cnt_rel[(size_t)rel * Nn + dst], 1);
}

__global__ __launch_bounds__(1024) void scan_kernel(const int* __restrict__ cnt, int* __restrict__ offs, int n) {
  __shared__ int part[1024];
  int t = threadIdx.x;
  int per = (n + 1023) / 1024;
  int base = t * per;
  int s = 0;
  for (int i = 0; i < per; ++i) { int idx = base + i; if (idx < n) s += cnt[idx]; }
  part[t] = s;
  __syncthreads();
  for (int o = 1; o < 1024; o <<= 1) {
    int v = (t >= o) ? part[t - o] : 0;
    __syncthreads();
    part[t] += v;
    __syncthreads();
  }
  int excl = (t == 0) ? 0 : part[t - 1];
  s = excl;
  for (int i = 0; i < per; ++i) { int idx = base + i; if (idx < n) { offs[idx] = s; s += cnt[idx]; } }
  if (t == 1023) offs[n] = part[1023];
}

__global__ void fillperm_kernel(const int* __restrict__ eidx, const int* __restrict__ offs,
                                int* fill, int* perm, int E) {
  int e = blockIdx.x * 256 + threadIdx.x;
  if (e >= E) return;
  int dst = eidx[E + e];
  int pos = offs[dst] + atomicAdd(&fill[dst], 1);
  perm[pos] = e;
}

// Per-layer weight conversion: Bt[n][seg*768+kk] = bf16( seg==0 ? roots[kk][n] : W[seg-1][kk][n] )
__global__ void wcat_kernel(const float* __restrict__ W, const float* __restrict__ R, u16* __restrict__ Bt) {
  __shared__ float t[32 * 33];
  int b = blockIdx.x;
  int s = b / 576, rem = b % 576;
  int kt = rem / 24, nt = rem % 24;
  const float* src = (s == 0) ? R : (W + (size_t)(s - 1) * DD * DD);
  int tj = threadIdx.x & 31, ti = threadIdx.x >> 5;  // ti 0..7
#pragma unroll
  for (int i = 0; i < 4; ++i) {
    int kk = kt * 32 + ti + i * 8;
    t[(ti + i * 8) * 33 + tj] = src[(size_t)kk * DD + nt * 32 + tj];
  }
  __syncthreads();
#pragma unroll
  for (int i = 0; i < 4; ++i) {
    int nn_ = nt * 32 + ti + i * 8;
    Bt[(size_t)nn_ * KK + (size_t)s * DD + kt * 32 + tj] = f2bf(t[tj * 33 + ti + i * 8]);
  }
}

// Copy h rows into segment 0 of A_cat
__global__ void copy_h_kernel(const u16* __restrict__ Hin, u16* __restrict__ Acat, int nn) {
  size_t total = (size_t)nn * (DD / 8);
  for (size_t i = (size_t)blockIdx.x * 256 + threadIdx.x; i < total; i += (size_t)gridDim.x * 256) {
    size_t r = i / (DD / 8), c = i % (DD / 8);
    *(uint4*)&Acat[r * KK + c * 8] = *(const uint4*)&Hin[r * DD + c * 8];
  }
}

// One block per destination node: accumulate incoming h[src] into LDS f32 [7][768],
// divide by per-relation counts, write bf16 into A_cat segments 1..7 (always, incl zeros).
__global__ __launch_bounds__(256) void aggregate_kernel(
    const u16* __restrict__ H, const int* __restrict__ esrc, const int* __restrict__ etype,
    const int* __restrict__ offs, const int* __restrict__ perm, const int* __restrict__ cnt_rel,
    u16* __restrict__ Acat, int node0, int Nn) {
  __shared__ float acc[NREL * DD];
  int v = node0 + blockIdx.x;
  int t = threadIdx.x;
  int j0 = t * 3;  // 256*3 = 768
  for (int i = t; i < NREL * DD; i += 256) acc[i] = 0.f;
  __syncthreads();
  int beg = offs[v], end = offs[v + 1];
  for (int e = beg; e < end; ++e) {
    int eid = perm[e];
    int src = esrc[eid];
    int rel = etype[eid] + 1;
    const u16* hr = H + (size_t)src * DD + j0;
    float* a = acc + rel * DD + j0;
    a[0] += b2f(hr[0]);
    a[1] += b2f(hr[1]);
    a[2] += b2f(hr[2]);
  }
  __syncthreads();
  size_t rowbase = (size_t)blockIdx.x * KK;
  for (int r = 0; r < NREL; ++r) {
    int c = cnt_rel[(size_t)r * Nn + v];
    float inv = (c > 0) ? 1.f / (float)c : 0.f;
    const float* a = acc + r * DD + j0;
    u16* o = Acat + rowbase + (size_t)(r + 1) * DD + j0;
    o[0] = f2bf(a[0] * inv);
    o[1] = f2bf(a[1] * inv);
    o[2] = f2bf(a[2] * inv);
  }
}

// ---------- 256x256 8-wave pipelined GEMM (BK=32, 4-deep LDS, st_16x32 swizzle) ----------
// C[M,768] = A[M,6144] @ Bt[768,6144]^T, epilogue +bias, ReLU, write bf16/f32.

__global__ __launch_bounds__(512, 2) void gemm256_kernel(
    const u16* __restrict__ A, const u16* __restrict__ Bt, const float* __restrict__ bias,
    u16* __restrict__ Hout, float* __restrict__ Cout, int Mvalid, int Mtiles) {
  // 4 buffers x (A 16KB + B 16KB) = 128 KB
  __shared__ u16 sm[4][16384];

  int tid = threadIdx.x;
  int lane = tid & 63;
  int wv = tid >> 6;            // 0..7
  int wm = wv >> 2, wn = wv & 3;

  // XCD-bijective block swizzle (m204), bn fastest so same-XCD blocks share A panels
  int nwg = Mtiles * 3;
  int orig = (int)blockIdx.x;
  int q8 = nwg >> 3, r8 = nwg & 7;
  int xcd = orig & 7, rank = orig >> 3;
  int wg = (xcd < r8 ? xcd * (q8 + 1) : r8 * (q8 + 1) + (xcd - r8) * q8) + rank;
  int bm = wg / 3, bn = wg % 3;

  // ---- staging precompute: inverse-swizzled global sources, linear LDS dest ----
  const char* gA[2];
  const char* gB[2];
#pragma unroll
  for (int j = 0; j < 2; ++j) {
    int qq = j * 8192 + tid * 16;
    int qp = qq ^ (((qq >> 9) & 1) << 5);              // unswizzle (involution)
    int row = ((qp >> 10) << 4) | ((qp >> 6) & 15);    // 0..255
    int kb  = qp & 63;                                  // byte within 32-col block
    int ra = bm * 256 + row; if (ra > Mvalid - 1) ra = Mvalid - 1;  // clamp into valid data
    int rb = bn * 256 + row;                            // < 768 always
    gA[j] = (const char*)A  + (size_t)ra * (KK * 2) + kb;
    gB[j] = (const char*)Bt + (size_t)rb * (KK * 2) + kb;
  }
  // swizzled ds_read lane offset: (rsel*64 + ksel*16) ^ ((rsel&8)<<2)
  int rsel = lane & 15;
  int laneoff = ((rsel * 64) + ((lane >> 4) * 16)) ^ ((rsel & 8) << 2);

  f32x4 acc[8][4];
#pragma unroll
  for (int m = 0; m < 8; ++m)
#pragma unroll
    for (int n = 0; n < 4; ++n) acc[m][n] = (f32x4){0.f, 0.f, 0.f, 0.f};

  const int NSTEP = KK / 32;  // 192

  auto STAGEA = [&](int t2, int buf) {
    size_t ko = (size_t)t2 * 64;  // bytes along K
    char* dst = (char*)&sm[buf][0];
#pragma unroll
    for (int j = 0; j < 2; ++j)
      gload16(gA[j] + ko, dst + j * 8192 + tid * 16);
  };
  auto STAGEB = [&](int t2, int buf) {
    size_t ko = (size_t)t2 * 64;
    char* dst = (char*)&sm[buf][8192];
#pragma unroll
    for (int j = 0; j < 2; ++j)
      gload16(gB[j] + ko, dst + j * 8192 + tid * 16);
  };

  // prologue: stage steps 0 and 1
  STAGEA(0, 0); STAGEB(0, 0);
  STAGEA(1, 1); STAGEB(1, 1);
  asm volatile("s_waitcnt vmcnt(4)" ::: "memory");  // step-0 data resident
  __builtin_amdgcn_s_barrier();
  __builtin_amdgcn_sched_barrier(0);

  for (int t = 0; t < NSTEP; ++t) {
    int cur = t & 3;
    int nxt = (t + 2) & 3;
    const char* sa = (const char*)&sm[cur][0];
    const char* sb = (const char*)&sm[cur][8192];

    // ---- phase A: read a[0..7], b[0..1]; stage A(t+2); MFMA n=0,1 ----
    short8 a8[8], b01[2], b23[2];
#pragma unroll
    for (int m = 0; m < 8; ++m)
      a8[m] = *(const short8*)(sa + (wm * 8 + m) * 1024 + laneoff);
#pragma unroll
    for (int n = 0; n < 2; ++n)
      b01[n] = *(const short8*)(sb + (wn * 4 + n) * 1024 + laneoff);
    if (t + 2 < NSTEP) STAGEA(t + 2, nxt);
    __builtin_amdgcn_s_barrier();
    __builtin_amdgcn_s_setprio(1);
#pragma unroll
    for (int m = 0; m < 8; ++m) {
      acc[m][0] = __builtin_amdgcn_mfma_f32_16x16x32_bf16(a8[m], b01[0], acc[m][0], 0, 0, 0);
      acc[m][1] = __builtin_amdgcn_mfma_f32_16x16x32_bf16(a8[m], b01[1], acc[m][1], 0, 0, 0);
    }
    __builtin_amdgcn_s_setprio(0);
    __builtin_amdgcn_s_barrier();

    // ---- phase B: read b[2..3]; stage B(t+2); MFMA n=2,3 ----
#pragma unroll
    for (int n = 0; n < 2; ++n)
      b23[n] = *(const short8*)(sb + (wn * 4 + 2 + n) * 1024 + laneoff);
    if (t + 2 < NSTEP) STAGEB(t + 2, nxt);
    __builtin_amdgcn_s_barrier();
    __builtin_amdgcn_s_setprio(1);
#pragma unroll
    for (int m = 0; m < 8; ++m) {
      acc[m][2] = __builtin_amdgcn_mfma_f32_16x16x32_bf16(a8[m], b23[0], acc[m][2], 0, 0, 0);
      acc[m][3] = __builtin_amdgcn_mfma_f32_16x16x32_bf16(a8[m], b23[1], acc[m][3], 0, 0, 0);
    }
    __builtin_amdgcn_s_setprio(0);
    // counted vmcnt: retire step t+1's stages (issued at t-1); keep step t's 4 in flight
    if (t + 3 < NSTEP) asm volatile("s_waitcnt vmcnt(4)" ::: "memory");
    else               asm volatile("s_waitcnt vmcnt(0)" ::: "memory");
    __builtin_amdgcn_s_barrier();
    __builtin_amdgcn_sched_barrier(0);
  }

  // ---- epilogue: bias + ReLU, write bf16 h_next / f32 out ----
  int rif = (lane >> 4) * 4;
  int cidx = lane & 15;
#pragma unroll
  for (int m = 0; m < 8; ++m) {
    int rl = bm * 256 + wm * 128 + m * 16 + rif;
#pragma unroll
    for (int n = 0; n < 4; ++n) {
      int c = bn * 256 + wn * 64 + n * 16 + cidx;
      float bv = bias[c];
#pragma unroll
      for (int j = 0; j < 4; ++j) {
        int r = rl + j;
        if (r < Mvalid) {
          float v = acc[m][n][j] + bv;
          v = v > 0.f ? v : 0.f;
          if (Hout) Hout[(size_t)r * DD + c] = f2bf(v);
          if (Cout) Cout[(size_t)r * DD + c] = v;
        }
      }
    }
  }
}

// ---------- host ----------

static inline size_t alignup(size_t x, size_t a) { return (x + a - 1) & ~(a - 1); }

extern "C" void kernel_launch(void* const* d_in, const int* in_sizes, int n_in,
                              void* d_out, int out_size, void* d_ws, size_t ws_size,
                              hipStream_t stream) {
  const float* x       = (const float*)d_in[0];
  const int*   eidx    = (const int*)d_in[1];
  const int*   etype   = (const int*)d_in[2];
  const float* weights = (const float*)d_in[3];
  const float* roots   = (const float*)d_in[4];
  const float* biases  = (const float*)d_in[5];
  float* out = (float*)d_out;

  const int Nn = in_sizes[0] / DD;  // 20000
  const int E  = in_sizes[2];       // 100000

  char* p = (char*)d_ws;
  size_t off = 0;
  auto carve = [&](size_t bytes) -> char* {
    char* r = p + off;
    off = alignup(off + bytes, 256);
    return r;
  };
  u16* H0      = (u16*)carve((size_t)Nn * DD * 2);
  u16* Bt      = (u16*)carve((size_t)DD * KK * 2);
  int* cnt_rel = (int*)carve((size_t)NREL * Nn * 4);
  int* cnt_dst = (int*)carve((size_t)Nn * 4);
  int* offs    = (int*)carve((size_t)(Nn + 1) * 4);
  int* fill    = (int*)carve((size_t)Nn * 4);
  int* perm    = (int*)carve((size_t)E * 4);

  size_t rem = (ws_size > off) ? (ws_size - off) : 0;
  int McCap = (int)(rem / ((size_t)KK * 2));
  int Mpad = ((Nn + 255) / 256) * 256;
  int Mc = (McCap < Mpad) ? (McCap & ~255) : Mpad;
  if (Mc < 256) return;  // workspace too small — fail visibly rather than corrupt
  u16* Acat = (u16*)(p + off);
  int nchunks = (Nn + Mc - 1) / Mc;
  u16* H1 = (u16*)d_out;  // bf16 ping buffer inside d_out (out_size*4 >= Nn*DD*2)

  (void)hipMemsetAsync(cnt_rel, 0, (size_t)NREL * Nn * 4, stream);
  (void)hipMemsetAsync(cnt_dst, 0, (size_t)Nn * 4, stream);
  (void)hipMemsetAsync(fill, 0, (size_t)Nn * 4, stream);

  int eg = (E + 255) / 256;
  count_kernel<<<eg, 256, 0, stream>>>(eidx, etype, cnt_dst, cnt_rel, E, Nn);
  scan_kernel<<<1, 1024, 0, stream>>>(cnt_dst, offs, Nn);
  fillperm_kernel<<<eg, 256, 0, stream>>>(eidx, offs, fill, perm, E);
  cast_x_kernel<<<2048, 256, 0, stream>>>(x, H0, (size_t)Nn * DD);

  const u16* Hin = H0;
  u16* Hnext = H1;
  for (int l = 0; l < NLAYERS; ++l) {
    wcat_kernel<<<8 * 576, 256, 0, stream>>>(weights + (size_t)l * NREL * DD * DD,
                                             roots + (size_t)l * DD * DD, Bt);
    for (int c = 0; c < nchunks; ++c) {
      int node0 = c * Mc;
      int nn = (Nn - node0 < Mc) ? (Nn - node0) : Mc;
      int copy16 = nn * (DD / 8);
      int cb = (copy16 + 255) / 256;
      if (cb > 2048) cb = 2048;
      copy_h_kernel<<<cb, 256, 0, stream>>>(Hin + (size_t)node0 * DD, Acat, nn);
      aggregate_kernel<<<nn, 256, 0, stream>>>(Hin, eidx, etype, offs, perm, cnt_rel,
                                               Acat, node0, Nn);
      int mt = (nn + 255) / 256;
      u16* ho = (l < NLAYERS - 1) ? (Hnext + (size_t)node0 * DD) : nullptr;
      float* co = (l == NLAYERS - 1) ? (out + (size_t)node0 * DD) : nullptr;
      gemm256_kernel<<<mt * 3, 512, 0, stream>>>(Acat, Bt, biases + (size_t)l * DD, ho, co, nn, mt);
    }
    const u16* t_ = Hin;
    Hin = Hnext;
    Hnext = (u16*)t_;
  }
}

// Round 3
// 1481.898 us; speedup vs baseline: 1.6785x; 1.0447x over previous
//
#include <hip/hip_runtime.h>

typedef unsigned short u16;
typedef unsigned int   u32;
typedef __attribute__((ext_vector_type(8))) short short8;
typedef __attribute__((ext_vector_type(4))) float f32x4;

#define DD      768
#define KK      6144   /* 8*768 : [root | W0..W6] concatenated on K */
#define NREL    7
#define NLAYERS 5

__device__ __forceinline__ float b2f(u16 v) {
  return __uint_as_float(((u32)v) << 16);
}
__device__ __forceinline__ u16 f2bf(float f) {
  u32 x = __float_as_uint(f);
  x += 0x7fffu + ((x >> 16) & 1u);
  return (u16)(x >> 16);
}
__device__ __forceinline__ void gload16(const void* g, void* l) {
  __builtin_amdgcn_global_load_lds(
      (const __attribute__((address_space(1))) void*)g,
      (__attribute__((address_space(3))) void*)l, 16, 0, 0);
}

// ---------- setup kernels ----------

__global__ void cast_x_kernel(const float* __restrict__ x, u16* __restrict__ H, size_t n) {
  for (size_t i = ((size_t)blockIdx.x * 256 + threadIdx.x) * 4; i < n; i += (size_t)gridDim.x * 256 * 4) {
    float4 v = *(const float4*)&x[i];
    u32 lo = (u32)f2bf(v.x) | ((u32)f2bf(v.y) << 16);
    u32 hi = (u32)f2bf(v.z) | ((u32)f2bf(v.w) << 16);
    uint2 o; o.x = lo; o.y = hi;
    *(uint2*)&H[i] = o;
  }
}

__global__ void count_kernel(const int* __restrict__ eidx, const int* __restrict__ etype,
                             int* cnt_dst, int* cnt_rel, int E, int Nn) {
  int e = blockIdx.x * 256 + threadIdx.x;
  if (e >= E) return;
  int dst = eidx[E + e];
  int rel = etype[e] + 1;
  atomicAdd(&cnt_dst[dst], 1);
  atomicAdd(&cnt_rel[(size_t)rel * Nn + dst], 1);
}

__global__ __launch_bounds__(1024) void scan_kernel(const int* __restrict__ cnt, int* __restrict__ offs, int n) {
  __shared__ int part[1024];
  int t = threadIdx.x;
  int per = (n + 1023) / 1024;
  int base = t * per;
  int s = 0;
  for (int i = 0; i < per; ++i) { int idx = base + i; if (idx < n) s += cnt[idx]; }
  part[t] = s;
  __syncthreads();
  for (int o = 1; o < 1024; o <<= 1) {
    int v = (t >= o) ? part[t - o] : 0;
    __syncthreads();
    part[t] += v;
    __syncthreads();
  }
  int excl = (t == 0) ? 0 : part[t - 1];
  s = excl;
  for (int i = 0; i < per; ++i) { int idx = base + i; if (idx < n) { offs[idx] = s; s += cnt[idx]; } }
  if (t == 1023) offs[n] = part[1023];
}

__global__ void fillperm_kernel(const int* __restrict__ eidx, const int* __restrict__ offs,
                                int* fill, int* perm, int E) {
  int e = blockIdx.x * 256 + threadIdx.x;
  if (e >= E) return;
  int dst = eidx[E + e];
  int pos = offs[dst] + atomicAdd(&fill[dst], 1);
  perm[pos] = e;
}

// Per-layer weight conversion: Bt[n][seg*768+kk] = bf16( seg==0 ? roots[kk][n] : W[seg-1][kk][n] )
__global__ void wcat_kernel(const float* __restrict__ W, const float* __restrict__ R, u16* __restrict__ Bt) {
  __shared__ float t[32 * 33];
  int b = blockIdx.x;
  int s = b / 576, rem = b % 576;
  int kt = rem / 24, nt = rem % 24;
  const float* src = (s == 0) ? R : (W + (size_t)(s - 1) * DD * DD);
  int tj = threadIdx.x & 31, ti = threadIdx.x >> 5;  // ti 0..7
#pragma unroll
  for (int i = 0; i < 4; ++i) {
    int kk = kt * 32 + ti + i * 8;
    t[(ti + i * 8) * 33 + tj] = src[(size_t)kk * DD + nt * 32 + tj];
  }
  __syncthreads();
#pragma unroll
  for (int i = 0; i < 4; ++i) {
    int nn_ = nt * 32 + ti + i * 8;
    Bt[(size_t)nn_ * KK + (size_t)s * DD + kt * 32 + tj] = f2bf(t[tj * 33 + ti + i * 8]);
  }
}

// Copy h rows into segment 0 of A_cat
__global__ void copy_h_kernel(const u16* __restrict__ Hin, u16* __restrict__ Acat, int nn) {
  size_t total = (size_t)nn * (DD / 8);
  for (size_t i = (size_t)blockIdx.x * 256 + threadIdx.x; i < total; i += (size_t)gridDim.x * 256) {
    size_t r = i / (DD / 8), c = i % (DD / 8);
    *(uint4*)&Acat[r * KK + c * 8] = *(const uint4*)&Hin[r * DD + c * 8];
  }
}

// One block (192 thr) per destination node. rel is wave-uniform per edge ->
// accumulate into per-thread registers via a 7-way switch; no LDS, no syncs.
__global__ __launch_bounds__(192) void aggregate_kernel(
    const u16* __restrict__ H, const int* __restrict__ esrc, const int* __restrict__ etype,
    const int* __restrict__ offs, const int* __restrict__ perm, const int* __restrict__ cnt_rel,
    u16* __restrict__ Acat, int node0, int Nn) {
  int v = node0 + blockIdx.x;
  int t = threadIdx.x;
  int j0 = t * 4;  // 192*4 = 768
  float a0[4] = {0,0,0,0}, a1[4] = {0,0,0,0}, a2[4] = {0,0,0,0}, a3[4] = {0,0,0,0};
  float a4[4] = {0,0,0,0}, a5[4] = {0,0,0,0}, a6[4] = {0,0,0,0};
  int beg = offs[v], end = offs[v + 1];
  for (int e = beg; e < end; ++e) {
    int eid = perm[e];
    int src = esrc[eid];
    int rel = etype[eid] + 1;
    uint2 w = *(const uint2*)&H[(size_t)src * DD + j0];
    float f0 = b2f((u16)(w.x & 0xffff));
    float f1 = b2f((u16)(w.x >> 16));
    float f2 = b2f((u16)(w.y & 0xffff));
    float f3 = b2f((u16)(w.y >> 16));
    switch (rel) {
      case 0: a0[0]+=f0; a0[1]+=f1; a0[2]+=f2; a0[3]+=f3; break;
      case 1: a1[0]+=f0; a1[1]+=f1; a1[2]+=f2; a1[3]+=f3; break;
      case 2: a2[0]+=f0; a2[1]+=f1; a2[2]+=f2; a2[3]+=f3; break;
      case 3: a3[0]+=f0; a3[1]+=f1; a3[2]+=f2; a3[3]+=f3; break;
      case 4: a4[0]+=f0; a4[1]+=f1; a4[2]+=f2; a4[3]+=f3; break;
      case 5: a5[0]+=f0; a5[1]+=f1; a5[2]+=f2; a5[3]+=f3; break;
      default: a6[0]+=f0; a6[1]+=f1; a6[2]+=f2; a6[3]+=f3; break;
    }
  }
  size_t rowbase = (size_t)blockIdx.x * KK;
  const float* regs[NREL] = {a0, a1, a2, a3, a4, a5, a6};
#pragma unroll
  for (int r = 0; r < NREL; ++r) {
    int c = cnt_rel[(size_t)r * Nn + v];
    float inv = (c > 0) ? 1.f / (float)c : 0.f;
    const float* a = regs[r];
    u32 lo = (u32)f2bf(a[0] * inv) | ((u32)f2bf(a[1] * inv) << 16);
    u32 hi = (u32)f2bf(a[2] * inv) | ((u32)f2bf(a[3] * inv) << 16);
    uint2 o; o.x = lo; o.y = hi;
    *(uint2*)&Acat[rowbase + (size_t)(r + 1) * DD + j0] = o;
  }
}

// ---------- 256x256 8-wave GEMM: BK=32, 4 LDS slots, depth-3 prefetch,
// register frag double-buffer (read step t+1 while MFMA'ing step t) ----------

__global__ __launch_bounds__(512, 2) void gemm256_kernel(
    const u16* __restrict__ A, const u16* __restrict__ Bt, const float* __restrict__ bias,
    u16* __restrict__ Hout, float* __restrict__ Cout, int Mvalid, int Mtiles) {
  // 4 slots x (A 16KB + B 16KB) = 128 KB
  __shared__ u16 sm[4][16384];

  int tid = threadIdx.x;
  int lane = tid & 63;
  int wv = tid >> 6;            // 0..7
  int wm = wv >> 2, wn = wv & 3;

  // XCD-bijective block swizzle (m204), bn fastest so same-XCD blocks share A panels
  int nwg = Mtiles * 3;
  int orig = (int)blockIdx.x;
  int q8 = nwg >> 3, r8 = nwg & 7;
  int xcd = orig & 7, rank = orig >> 3;
  int wg = (xcd < r8 ? xcd * (q8 + 1) : r8 * (q8 + 1) + (xcd - r8) * q8) + rank;
  int bm = wg / 3, bn = wg % 3;

  // staging: inverse-swizzled global sources, linear LDS dest (rule #21)
  const char* gA[2];
  const char* gB[2];
#pragma unroll
  for (int j = 0; j < 2; ++j) {
    int qq = j * 8192 + tid * 16;
    int qp = qq ^ (((qq >> 9) & 1) << 5);              // unswizzle (involution)
    int row = ((qp >> 10) << 4) | ((qp >> 6) & 15);    // 0..255
    int kb  = qp & 63;                                  // byte within 32-col block
    gA[j] = (const char*)A  + (size_t)(bm * 256 + row) * (KK * 2) + kb;
    gB[j] = (const char*)Bt + (size_t)(bn * 256 + row) * (KK * 2) + kb;
  }
  // swizzled ds_read lane offset
  int rsel = lane & 15;
  int laneoff = ((rsel * 64) + ((lane >> 4) * 16)) ^ ((rsel & 8) << 2);

  f32x4 acc[8][4];
#pragma unroll
  for (int m = 0; m < 8; ++m)
#pragma unroll
    for (int n = 0; n < 4; ++n) acc[m][n] = (f32x4){0.f, 0.f, 0.f, 0.f};

  const int NSTEP = KK / 32;  // 192

#define STAGE(t2)                                                        \
  do {                                                                   \
    int s_ = (t2) & 3;                                                   \
    size_t ko_ = (size_t)(t2) * 64;                                      \
    char* d_ = (char*)&sm[s_][0];                                        \
    gload16(gA[0] + ko_, d_ + tid * 16);                                 \
    gload16(gA[1] + ko_, d_ + 8192 + tid * 16);                          \
    gload16(gB[0] + ko_, d_ + 16384 + tid * 16);                         \
    gload16(gB[1] + ko_, d_ + 16384 + 8192 + tid * 16);                  \
  } while (0)

#define READF(t2, ar, br)                                                \
  do {                                                                   \
    const char* base_ = (const char*)&sm[(t2) & 3][0];                   \
    _Pragma("unroll")                                                    \
    for (int m = 0; m < 8; ++m)                                          \
      ar[m] = *(const short8*)(base_ + (wm * 8 + m) * 1024 + laneoff);   \
    _Pragma("unroll")                                                    \
    for (int n = 0; n < 4; ++n)                                          \
      br[n] = *(const short8*)(base_ + 16384 + (wn * 4 + n) * 1024 + laneoff); \
  } while (0)

#define MFMA32(ar, br)                                                   \
  do {                                                                   \
    _Pragma("unroll")                                                    \
    for (int m = 0; m < 8; ++m)                                          \
      _Pragma("unroll")                                                  \
      for (int n = 0; n < 4; ++n)                                        \
        acc[m][n] = __builtin_amdgcn_mfma_f32_16x16x32_bf16(ar[m], br[n], acc[m][n], 0, 0, 0); \
  } while (0)

  short8 aE[8], bE[4], aO[8], bO[4];

  // prologue: stage steps 0..2; steps 0,1 resident after vmcnt(4)
  STAGE(0); STAGE(1); STAGE(2);
  asm volatile("s_waitcnt vmcnt(4)" ::: "memory");
  __builtin_amdgcn_s_barrier();
  __builtin_amdgcn_sched_barrier(0);
  READF(0, aE, bE);

  for (int t = 0; t < NSTEP; t += 2) {
    // even half: MFMA step t (aE), read step t+1, stage step t+3
    if (t + 3 < NSTEP) STAGE(t + 3);
    READF(t + 1, aO, bO);
    __builtin_amdgcn_sched_barrier(0);
    __builtin_amdgcn_s_setprio(1);
    MFMA32(aE, bE);
    __builtin_amdgcn_s_setprio(0);
    asm volatile("s_waitcnt vmcnt(4)" ::: "memory");
    __builtin_amdgcn_s_barrier();
    __builtin_amdgcn_sched_barrier(0);

    // odd half: MFMA step t+1 (aO), read step t+2, stage step t+4
    if (t + 4 < NSTEP) STAGE(t + 4);
    if (t + 2 < NSTEP) READF(t + 2, aE, bE);
    __builtin_amdgcn_sched_barrier(0);
    __builtin_amdgcn_s_setprio(1);
    MFMA32(aO, bO);
    __builtin_amdgcn_s_setprio(0);
    asm volatile("s_waitcnt vmcnt(4)" ::: "memory");
    __builtin_amdgcn_s_barrier();
    __builtin_amdgcn_sched_barrier(0);
  }
#undef STAGE
#undef READF
#undef MFMA32

  // ---- epilogue: bias + ReLU, write bf16 h_next / f32 out ----
  int rif = (lane >> 4) * 4;
  int cidx = lane & 15;
#pragma unroll
  for (int m = 0; m < 8; ++m) {
    int rl = bm * 256 + wm * 128 + m * 16 + rif;
#pragma unroll
    for (int n = 0; n < 4; ++n) {
      int c = bn * 256 + wn * 64 + n * 16 + cidx;
      float bv = bias[c];
#pragma unroll
      for (int j = 0; j < 4; ++j) {
        int r = rl + j;
        if (r < Mvalid) {
          float v = acc[m][n][j] + bv;
          v = v > 0.f ? v : 0.f;
          if (Hout) Hout[(size_t)r * DD + c] = f2bf(v);
          if (Cout) Cout[(size_t)r * DD + c] = v;
        }
      }
    }
  }
}

// ---------- host ----------

static inline size_t alignup(size_t x, size_t a) { return (x + a - 1) & ~(a - 1); }

extern "C" void kernel_launch(void* const* d_in, const int* in_sizes, int n_in,
                              void* d_out, int out_size, void* d_ws, size_t ws_size,
                              hipStream_t stream) {
  const float* x       = (const float*)d_in[0];
  const int*   eidx    = (const int*)d_in[1];
  const int*   etype   = (const int*)d_in[2];
  const float* weights = (const float*)d_in[3];
  const float* roots   = (const float*)d_in[4];
  const float* biases  = (const float*)d_in[5];
  float* out = (float*)d_out;

  const int Nn = in_sizes[0] / DD;  // 20000
  const int E  = in_sizes[2];       // 100000

  char* p = (char*)d_ws;
  size_t off = 0;
  auto carve = [&](size_t bytes) -> char* {
    char* r = p + off;
    off = alignup(off + bytes, 256);
    return r;
  };
  u16* H0      = (u16*)carve((size_t)Nn * DD * 2);
  u16* Bt      = (u16*)carve((size_t)DD * KK * 2);
  int* cnt_rel = (int*)carve((size_t)NREL * Nn * 4);
  int* cnt_dst = (int*)carve((size_t)Nn * 4);
  int* offs    = (int*)carve((size_t)(Nn + 1) * 4);
  int* fill    = (int*)carve((size_t)Nn * 4);
  int* perm    = (int*)carve((size_t)E * 4);

  size_t rem = (ws_size > off) ? (ws_size - off) : 0;
  int McCap = (int)(rem / ((size_t)KK * 2));
  int Mpad = ((Nn + 255) / 256) * 256;
  int Mc = (McCap < Mpad) ? (McCap & ~255) : Mpad;
  if (Mc < 256) return;  // workspace too small — fail visibly rather than corrupt
  u16* Acat = (u16*)(p + off);
  int nchunks = (Nn + Mc - 1) / Mc;
  u16* H1 = (u16*)d_out;  // bf16 ping buffer inside d_out (out_size*4 >= Nn*DD*2)

  (void)hipMemsetAsync(cnt_rel, 0, (size_t)NREL * Nn * 4, stream);
  (void)hipMemsetAsync(cnt_dst, 0, (size_t)Nn * 4, stream);
  (void)hipMemsetAsync(fill, 0, (size_t)Nn * 4, stream);

  int eg = (E + 255) / 256;
  count_kernel<<<eg, 256, 0, stream>>>(eidx, etype, cnt_dst, cnt_rel, E, Nn);
  scan_kernel<<<1, 1024, 0, stream>>>(cnt_dst, offs, Nn);
  fillperm_kernel<<<eg, 256, 0, stream>>>(eidx, offs, fill, perm, E);
  cast_x_kernel<<<2048, 256, 0, stream>>>(x, H0, (size_t)Nn * DD);

  const u16* Hin = H0;
  u16* Hnext = H1;
  for (int l = 0; l < NLAYERS; ++l) {
    wcat_kernel<<<8 * 576, 256, 0, stream>>>(weights + (size_t)l * NREL * DD * DD,
                                             roots + (size_t)l * DD * DD, Bt);
    for (int c = 0; c < nchunks; ++c) {
      int node0 = c * Mc;
      int nn = (Nn - node0 < Mc) ? (Nn - node0) : Mc;
      int copy16 = nn * (DD / 8);
      int cb = (copy16 + 255) / 256;
      if (cb > 2048) cb = 2048;
      copy_h_kernel<<<cb, 256, 0, stream>>>(Hin + (size_t)node0 * DD, Acat, nn);
      aggregate_kernel<<<nn, 192, 0, stream>>>(Hin, eidx, etype, offs, perm, cnt_rel,
                                               Acat, node0, Nn);
      int mt = (nn + 255) / 256;
      u16* ho = (l < NLAYERS - 1) ? (Hnext + (size_t)node0 * DD) : nullptr;
      float* co = (l == NLAYERS - 1) ? (out + (size_t)node0 * DD) : nullptr;
      gemm256_kernel<<<mt * 3, 512, 0, stream>>>(Acat, Bt, biases + (size_t)l * DD, ho, co, nn, mt);
    }
    const u16* t_ = Hin;
    Hin = Hnext;
    Hnext = (u16*)t_;
  }
}

// Round 4
// 1423.678 us; speedup vs baseline: 1.7471x; 1.0409x over previous
//
#include <hip/hip_runtime.h>

typedef unsigned short u16;
typedef unsigned int   u32;
typedef __attribute__((ext_vector_type(8))) short short8;
typedef __attribute__((ext_vector_type(4))) float f32x4;

#define DD      768
#define KK      6144   /* 8*768 : [root | W0..W6] concatenated on K */
#define NREL    7
#define NLAYERS 5

__device__ __forceinline__ float b2f(u16 v) {
  return __uint_as_float(((u32)v) << 16);
}
__device__ __forceinline__ u16 f2bf(float f) {
  u32 x = __float_as_uint(f);
  x += 0x7fffu + ((x >> 16) & 1u);
  return (u16)(x >> 16);
}
__device__ __forceinline__ void gload16(const void* g, void* l) {
  __builtin_amdgcn_global_load_lds(
      (const __attribute__((address_space(1))) void*)g,
      (__attribute__((address_space(3))) void*)l, 16, 0, 0);
}

// ---------- setup kernels ----------

__global__ void cast_x_kernel(const float* __restrict__ x, u16* __restrict__ H, size_t n) {
  for (size_t i = ((size_t)blockIdx.x * 256 + threadIdx.x) * 4; i < n; i += (size_t)gridDim.x * 256 * 4) {
    float4 v = *(const float4*)&x[i];
    u32 lo = (u32)f2bf(v.x) | ((u32)f2bf(v.y) << 16);
    u32 hi = (u32)f2bf(v.z) | ((u32)f2bf(v.w) << 16);
    uint2 o; o.x = lo; o.y = hi;
    *(uint2*)&H[i] = o;
  }
}

__global__ void count_kernel(const int* __restrict__ eidx, const int* __restrict__ etype,
                             int* cnt_dst, int* cnt_rel, int E, int Nn) {
  int e = blockIdx.x * 256 + threadIdx.x;
  if (e >= E) return;
  int dst = eidx[E + e];
  int rel = etype[e] + 1;
  atomicAdd(&cnt_dst[dst], 1);
  atomicAdd(&cnt_rel[(size_t)rel * Nn + dst], 1);
}

__global__ __launch_bounds__(1024) void scan_kernel(const int* __restrict__ cnt, int* __restrict__ offs, int n) {
  __shared__ int part[1024];
  int t = threadIdx.x;
  int per = (n + 1023) / 1024;
  int base = t * per;
  int s = 0;
  for (int i = 0; i < per; ++i) { int idx = base + i; if (idx < n) s += cnt[idx]; }
  part[t] = s;
  __syncthreads();
  for (int o = 1; o < 1024; o <<= 1) {
    int v = (t >= o) ? part[t - o] : 0;
    __syncthreads();
    part[t] += v;
    __syncthreads();
  }
  int excl = (t == 0) ? 0 : part[t - 1];
  s = excl;
  for (int i = 0; i < per; ++i) { int idx = base + i; if (idx < n) { offs[idx] = s; s += cnt[idx]; } }
  if (t == 1023) offs[n] = part[1023];
}

__global__ void fillperm_kernel(const int* __restrict__ eidx, const int* __restrict__ offs,
                                int* fill, int* perm, int E) {
  int e = blockIdx.x * 256 + threadIdx.x;
  if (e >= E) return;
  int dst = eidx[E + e];
  int pos = offs[dst] + atomicAdd(&fill[dst], 1);
  perm[pos] = e;
}

// Per-layer weight conversion: Bt[n][seg*768+kk] = bf16( seg==0 ? roots[kk][n] : W[seg-1][kk][n] )
__global__ void wcat_kernel(const float* __restrict__ W, const float* __restrict__ R, u16* __restrict__ Bt) {
  __shared__ float t[32 * 33];
  int b = blockIdx.x;
  int s = b / 576, rem = b % 576;
  int kt = rem / 24, nt = rem % 24;
  const float* src = (s == 0) ? R : (W + (size_t)(s - 1) * DD * DD);
  int tj = threadIdx.x & 31, ti = threadIdx.x >> 5;  // ti 0..7
#pragma unroll
  for (int i = 0; i < 4; ++i) {
    int kk = kt * 32 + ti + i * 8;
    t[(ti + i * 8) * 33 + tj] = src[(size_t)kk * DD + nt * 32 + tj];
  }
  __syncthreads();
#pragma unroll
  for (int i = 0; i < 4; ++i) {
    int nn_ = nt * 32 + ti + i * 8;
    Bt[(size_t)nn_ * KK + (size_t)s * DD + kt * 32 + tj] = f2bf(t[tj * 33 + ti + i * 8]);
  }
}

// One block (192 thr) per destination node. rel is wave-uniform per edge ->
// accumulate into per-thread registers via a 7-way switch; no LDS, no syncs.
// Also copies own row Hin[v] into segment 0 (fused former copy_h).
__global__ __launch_bounds__(192) void aggregate_kernel(
    const u16* __restrict__ H, const int* __restrict__ esrc, const int* __restrict__ etype,
    const int* __restrict__ offs, const int* __restrict__ perm, const int* __restrict__ cnt_rel,
    u16* __restrict__ Acat, int node0, int Nn) {
  int v = node0 + blockIdx.x;
  int t = threadIdx.x;
  int j0 = t * 4;  // 192*4 = 768
  size_t rowbase = (size_t)blockIdx.x * KK;
  // segment 0: copy own row
  *(uint2*)&Acat[rowbase + j0] = *(const uint2*)&H[(size_t)v * DD + j0];
  float a0[4] = {0,0,0,0}, a1[4] = {0,0,0,0}, a2[4] = {0,0,0,0}, a3[4] = {0,0,0,0};
  float a4[4] = {0,0,0,0}, a5[4] = {0,0,0,0}, a6[4] = {0,0,0,0};
  int beg = offs[v], end = offs[v + 1];
  for (int e = beg; e < end; ++e) {
    int eid = perm[e];
    int src = esrc[eid];
    int rel = etype[eid] + 1;
    uint2 w = *(const uint2*)&H[(size_t)src * DD + j0];
    float f0 = b2f((u16)(w.x & 0xffff));
    float f1 = b2f((u16)(w.x >> 16));
    float f2 = b2f((u16)(w.y & 0xffff));
    float f3 = b2f((u16)(w.y >> 16));
    switch (rel) {
      case 0: a0[0]+=f0; a0[1]+=f1; a0[2]+=f2; a0[3]+=f3; break;
      case 1: a1[0]+=f0; a1[1]+=f1; a1[2]+=f2; a1[3]+=f3; break;
      case 2: a2[0]+=f0; a2[1]+=f1; a2[2]+=f2; a2[3]+=f3; break;
      case 3: a3[0]+=f0; a3[1]+=f1; a3[2]+=f2; a3[3]+=f3; break;
      case 4: a4[0]+=f0; a4[1]+=f1; a4[2]+=f2; a4[3]+=f3; break;
      case 5: a5[0]+=f0; a5[1]+=f1; a5[2]+=f2; a5[3]+=f3; break;
      default: a6[0]+=f0; a6[1]+=f1; a6[2]+=f2; a6[3]+=f3; break;
    }
  }
  const float* regs[NREL] = {a0, a1, a2, a3, a4, a5, a6};
#pragma unroll
  for (int r = 0; r < NREL; ++r) {
    int c = cnt_rel[(size_t)r * Nn + v];
    float inv = (c > 0) ? 1.f / (float)c : 0.f;
    const float* a = regs[r];
    u32 lo = (u32)f2bf(a[0] * inv) | ((u32)f2bf(a[1] * inv) << 16);
    u32 hi = (u32)f2bf(a[2] * inv) | ((u32)f2bf(a[3] * inv) << 16);
    uint2 o; o.x = lo; o.y = hi;
    *(uint2*)&Acat[rowbase + (size_t)(r + 1) * DD + j0] = o;
  }
}

// ---------- 256x256 8-wave GEMM: BK=32, 4 LDS slots, depth-3 prefetch.
// Per half: MFMA cluster FIRST (regs read last half), next-half ds_reads +
// stage loads interleaved between 8-MFMA groups so LDS pipe overlaps matrix pipe.

__global__ __launch_bounds__(512, 2) void gemm256_kernel(
    const u16* __restrict__ A, const u16* __restrict__ Bt, const float* __restrict__ bias,
    u16* __restrict__ Hout, float* __restrict__ Cout, int Mvalid, int Mtiles) {
  // 4 slots x (A 16KB + B 16KB) = 128 KB
  __shared__ u16 sm[4][16384];

  int tid = threadIdx.x;
  int lane = tid & 63;
  int wv = tid >> 6;            // 0..7
  int wm = wv >> 2, wn = wv & 3;

  // XCD-bijective block swizzle (m204), bn fastest so same-XCD blocks share A panels
  int nwg = Mtiles * 3;
  int orig = (int)blockIdx.x;
  int q8 = nwg >> 3, r8 = nwg & 7;
  int xcd = orig & 7, rank = orig >> 3;
  int wg = (xcd < r8 ? xcd * (q8 + 1) : r8 * (q8 + 1) + (xcd - r8) * q8) + rank;
  int bm = wg / 3, bn = wg % 3;

  // staging: inverse-swizzled global sources, linear LDS dest (rule #21)
  const char* gA[2];
  const char* gB[2];
#pragma unroll
  for (int j = 0; j < 2; ++j) {
    int qq = j * 8192 + tid * 16;
    int qp = qq ^ (((qq >> 9) & 1) << 5);              // unswizzle (involution)
    int row = ((qp >> 10) << 4) | ((qp >> 6) & 15);    // 0..255
    int kb  = qp & 63;                                  // byte within 32-col block
    gA[j] = (const char*)A  + (size_t)(bm * 256 + row) * (KK * 2) + kb;
    gB[j] = (const char*)Bt + (size_t)(bn * 256 + row) * (KK * 2) + kb;
  }
  // swizzled ds_read lane offset
  int rsel = lane & 15;
  int laneoff = ((rsel * 64) + ((lane >> 4) * 16)) ^ ((rsel & 8) << 2);

  f32x4 acc[8][4];
#pragma unroll
  for (int m = 0; m < 8; ++m)
#pragma unroll
    for (int n = 0; n < 4; ++n) acc[m][n] = (f32x4){0.f, 0.f, 0.f, 0.f};

  const int NSTEP = KK / 32;  // 192

#define RD_A(base_, r_)  (*(const short8*)((base_) + (r_) * 1024 + laneoff))
#define RD_B(base_, r_)  (*(const short8*)((base_) + 16384 + (r_) * 1024 + laneoff))

#define STAGE_FULL(t2)                                                   \
  do {                                                                   \
    int s_ = (t2) & 3;                                                   \
    size_t ko_ = (size_t)(t2) * 64;                                      \
    char* d_ = (char*)&sm[s_][0];                                        \
    gload16(gA[0] + ko_, d_ + tid * 16);                                 \
    gload16(gA[1] + ko_, d_ + 8192 + tid * 16);                          \
    gload16(gB[0] + ko_, d_ + 16384 + tid * 16);                         \
    gload16(gB[1] + ko_, d_ + 16384 + 8192 + tid * 16);                  \
  } while (0)

#define MFMA8(AR, BR, M0)                                                \
  do {                                                                   \
    _Pragma("unroll")                                                    \
    for (int n_ = 0; n_ < 4; ++n_) {                                     \
      acc[(M0)][n_]     = __builtin_amdgcn_mfma_f32_16x16x32_bf16(AR[(M0)],     BR[n_], acc[(M0)][n_],     0, 0, 0); \
      acc[(M0) + 1][n_] = __builtin_amdgcn_mfma_f32_16x16x32_bf16(AR[(M0) + 1], BR[n_], acc[(M0) + 1][n_], 0, 0, 0); \
    }                                                                    \
  } while (0)

// One K-step: MFMA on (AC,BC); interleave reads of slot (tcur+1) into (AN,BN_)
// and clamped stage of step tcur+3; counted vmcnt; barrier.
#define HALF(tcur, AC, BC, AN, BN_)                                      \
  do {                                                                   \
    const char* rb_ = (const char*)&sm[((tcur) + 1) & 3][0];             \
    int tc_ = (tcur) + 3;                                                \
    int ts_ = tc_ & 3;                                                   \
    int tk_ = tc_ < NSTEP ? tc_ : NSTEP - 1;                             \
    size_t ko_ = (size_t)tk_ * 64;                                       \
    char* sd_ = (char*)&sm[ts_][0];                                      \
    __builtin_amdgcn_s_setprio(1);                                       \
    MFMA8(AC, BC, 0);                                                    \
    __builtin_amdgcn_sched_barrier(0);                                   \
    AN[0] = RD_A(rb_, wm * 8 + 0);                                       \
    AN[1] = RD_A(rb_, wm * 8 + 1);                                       \
    AN[2] = RD_A(rb_, wm * 8 + 2);                                       \
    gload16(gA[0] + ko_, sd_ + tid * 16);                                \
    __builtin_amdgcn_sched_barrier(0);                                   \
    MFMA8(AC, BC, 2);                                                    \
    __builtin_amdgcn_sched_barrier(0);                                   \
    AN[3] = RD_A(rb_, wm * 8 + 3);                                       \
    AN[4] = RD_A(rb_, wm * 8 + 4);                                       \
    AN[5] = RD_A(rb_, wm * 8 + 5);                                       \
    gload16(gA[1] + ko_, sd_ + 8192 + tid * 16);                         \
    __builtin_amdgcn_sched_barrier(0);                                   \
    MFMA8(AC, BC, 4);                                                    \
    __builtin_amdgcn_sched_barrier(0);                                   \
    AN[6] = RD_A(rb_, wm * 8 + 6);                                       \
    AN[7] = RD_A(rb_, wm * 8 + 7);                                       \
    BN_[0] = RD_B(rb_, wn * 4 + 0);                                      \
    gload16(gB[0] + ko_, sd_ + 16384 + tid * 16);                        \
    __builtin_amdgcn_sched_barrier(0);                                   \
    MFMA8(AC, BC, 6);                                                    \
    __builtin_amdgcn_sched_barrier(0);                                   \
    BN_[1] = RD_B(rb_, wn * 4 + 1);                                      \
    BN_[2] = RD_B(rb_, wn * 4 + 2);                                      \
    BN_[3] = RD_B(rb_, wn * 4 + 3);                                      \
    gload16(gB[1] + ko_, sd_ + 16384 + 8192 + tid * 16);                 \
    __builtin_amdgcn_s_setprio(0);                                       \
    asm volatile("s_waitcnt vmcnt(4)" ::: "memory");                     \
    __builtin_amdgcn_s_barrier();                                        \
    __builtin_amdgcn_sched_barrier(0);                                   \
  } while (0)

  short8 aE[8], bE[4], aO[8], bO[4];

  // prologue: stage steps 0..2; retire 0,1; read step-0 frags
  STAGE_FULL(0); STAGE_FULL(1); STAGE_FULL(2);
  asm volatile("s_waitcnt vmcnt(4)" ::: "memory");
  __builtin_amdgcn_s_barrier();
  __builtin_amdgcn_sched_barrier(0);
#pragma unroll
  for (int m = 0; m < 8; ++m) aE[m] = RD_A((const char*)&sm[0][0], wm * 8 + m);
#pragma unroll
  for (int n = 0; n < 4; ++n) bE[n] = RD_B((const char*)&sm[0][0], wn * 4 + n);
  __builtin_amdgcn_sched_barrier(0);

  for (int t = 0; t < NSTEP - 2; t += 2) {
    HALF(t,     aE, bE, aO, bO);
    HALF(t + 1, aO, bO, aE, bE);
  }
  HALF(NSTEP - 2, aE, bE, aO, bO);
  // final K-step: MFMA only
  __builtin_amdgcn_s_setprio(1);
  MFMA8(aO, bO, 0); MFMA8(aO, bO, 2); MFMA8(aO, bO, 4); MFMA8(aO, bO, 6);
  __builtin_amdgcn_s_setprio(0);

#undef HALF
#undef MFMA8
#undef STAGE_FULL
#undef RD_A
#undef RD_B

  // ---- epilogue: bias + ReLU, write bf16 h_next / f32 out ----
  int rif = (lane >> 4) * 4;
  int cidx = lane & 15;
#pragma unroll
  for (int m = 0; m < 8; ++m) {
    int rl = bm * 256 + wm * 128 + m * 16 + rif;
#pragma unroll
    for (int n = 0; n < 4; ++n) {
      int c = bn * 256 + wn * 64 + n * 16 + cidx;
      float bv = bias[c];
#pragma unroll
      for (int j = 0; j < 4; ++j) {
        int r = rl + j;
        if (r < Mvalid) {
          float v = acc[m][n][j] + bv;
          v = v > 0.f ? v : 0.f;
          if (Hout) Hout[(size_t)r * DD + c] = f2bf(v);
          if (Cout) Cout[(size_t)r * DD + c] = v;
        }
      }
    }
  }
}

// ---------- host ----------

static inline size_t alignup(size_t x, size_t a) { return (x + a - 1) & ~(a - 1); }

extern "C" void kernel_launch(void* const* d_in, const int* in_sizes, int n_in,
                              void* d_out, int out_size, void* d_ws, size_t ws_size,
                              hipStream_t stream) {
  const float* x       = (const float*)d_in[0];
  const int*   eidx    = (const int*)d_in[1];
  const int*   etype   = (const int*)d_in[2];
  const float* weights = (const float*)d_in[3];
  const float* roots   = (const float*)d_in[4];
  const float* biases  = (const float*)d_in[5];
  float* out = (float*)d_out;

  const int Nn = in_sizes[0] / DD;  // 20000
  const int E  = in_sizes[2];       // 100000

  char* p = (char*)d_ws;
  size_t off = 0;
  auto carve = [&](size_t bytes) -> char* {
    char* r = p + off;
    off = alignup(off + bytes, 256);
    return r;
  };
  u16* H0      = (u16*)carve((size_t)Nn * DD * 2);
  u16* Bt      = (u16*)carve((size_t)DD * KK * 2);
  int* cnt_rel = (int*)carve((size_t)NREL * Nn * 4);
  int* cnt_dst = (int*)carve((size_t)Nn * 4);
  int* offs    = (int*)carve((size_t)(Nn + 1) * 4);
  int* fill    = (int*)carve((size_t)Nn * 4);
  int* perm    = (int*)carve((size_t)E * 4);

  size_t rem = (ws_size > off) ? (ws_size - off) : 0;
  int McCap = (int)(rem / ((size_t)KK * 2));
  int Mpad = ((Nn + 255) / 256) * 256;
  int Mc = (McCap < Mpad) ? (McCap & ~255) : Mpad;
  if (Mc < 256) return;  // workspace too small — fail visibly rather than corrupt
  u16* Acat = (u16*)(p + off);
  int nchunks = (Nn + Mc - 1) / Mc;
  u16* H1 = (u16*)d_out;  // bf16 ping buffer inside d_out (out_size*4 >= Nn*DD*2)

  (void)hipMemsetAsync(cnt_rel, 0, (size_t)NREL * Nn * 4, stream);
  (void)hipMemsetAsync(cnt_dst, 0, (size_t)Nn * 4, stream);
  (void)hipMemsetAsync(fill, 0, (size_t)Nn * 4, stream);

  int eg = (E + 255) / 256;
  count_kernel<<<eg, 256, 0, stream>>>(eidx, etype, cnt_dst, cnt_rel, E, Nn);
  scan_kernel<<<1, 1024, 0, stream>>>(cnt_dst, offs, Nn);
  fillperm_kernel<<<eg, 256, 0, stream>>>(eidx, offs, fill, perm, E);
  cast_x_kernel<<<2048, 256, 0, stream>>>(x, H0, (size_t)Nn * DD);

  const u16* Hin = H0;
  u16* Hnext = H1;
  for (int l = 0; l < NLAYERS; ++l) {
    wcat_kernel<<<8 * 576, 256, 0, stream>>>(weights + (size_t)l * NREL * DD * DD,
                                             roots + (size_t)l * DD * DD, Bt);
    for (int c = 0; c < nchunks; ++c) {
      int node0 = c * Mc;
      int nn = (Nn - node0 < Mc) ? (Nn - node0) : Mc;
      aggregate_kernel<<<nn, 192, 0, stream>>>(Hin, eidx, etype, offs, perm, cnt_rel,
                                               Acat, node0, Nn);
      int mt = (nn + 255) / 256;
      u16* ho = (l < NLAYERS - 1) ? (Hnext + (size_t)node0 * DD) : nullptr;
      float* co = (l == NLAYERS - 1) ? (out + (size_t)node0 * DD) : nullptr;
      gemm256_kernel<<<mt * 3, 512, 0, stream>>>(Acat, Bt, biases + (size_t)l * DD, ho, co, nn, mt);
    }
    const u16* t_ = Hin;
    Hin = Hnext;
    Hnext = (u16*)t_;
  }
}